// Round 7
// baseline (166.243 us; speedup 1.0000x reference)
//
#include <hip/hip_runtime.h>

// B=8, S=4096, E=256, H=4, DK=64. Tokens = 32768.
// Head-mix "attention": 4 GEMMs (32768x256 @ 256x256) + per-token 4x4 softmax.
// Round-7 = round-6 (2 LDS buffers, in-register head-mix, 4 blocks/CU) with
// register-liveness engineered to kill the spills rocprof exposed (VGPR=64,
// WRITE_SIZE 2x): projection order K->V->Q, V packed to bf16 immediately,
// so peak pressure ~95 VGPR < 128 cap of __launch_bounds__(256,4).

typedef __bf16 bf16x8 __attribute__((ext_vector_type(8)));
typedef __bf16 bf16x4 __attribute__((ext_vector_type(4)));
typedef float f32x4 __attribute__((ext_vector_type(4)));

#define LDW 264   // LDS row stride (bf16 elems): 256 + 8 pad

#define MFMA(a, b, c) __builtin_amdgcn_mfma_f32_16x16x32_bf16((a), (b), (c), 0, 0, 0)

// ---------- prep: pack W into fragment-contiguous bf16, interleaved-n ----------
// frag (p, j, g, kk): lane (lh=lane&15, lq=lane>>4) holds
//   W_p[g*64 + j*16 + lh][kk*32 + lq*8 .. +8)   (16 B)
// at Wpk[frag_id*512 + lane*8], frag_id = ((p*4+j)*4+g)*8+kk.
__global__ void pack_wfrag(const float* __restrict__ Wq, const float* __restrict__ Wk,
                           const float* __restrict__ Wv, const float* __restrict__ Wo,
                           __bf16* __restrict__ Wpk) {
  const int f    = blockIdx.x;          // 0..511
  const int lane = threadIdx.x;         // 0..63
  const int kk = f & 7;
  const int g  = (f >> 3) & 3;
  const int j  = (f >> 5) & 3;
  const int p  = f >> 7;
  const float* W = (p == 0) ? Wq : (p == 1) ? Wk : (p == 2) ? Wv : Wo;
  const int lh = lane & 15, lq = lane >> 4;
  const int n  = g * 64 + j * 16 + lh;
  const int k0 = kk * 32 + lq * 8;
  const float4 s0 = *(const float4*)&W[n * 256 + k0];
  const float4 s1 = *(const float4*)&W[n * 256 + k0 + 4];
  bf16x8 r;
  r[0] = (__bf16)s0.x; r[1] = (__bf16)s0.y; r[2] = (__bf16)s0.z; r[3] = (__bf16)s0.w;
  r[4] = (__bf16)s1.x; r[5] = (__bf16)s1.y; r[6] = (__bf16)s1.z; r[7] = (__bf16)s1.w;
  *(bf16x8*)&Wpk[(size_t)f * 512 + lane * 8] = r;
}

// C/D scatter (+bias) -> bf16 LDS; acc slot g maps to col g*64 + colbase + lh.
__device__ __forceinline__ void store_cd(__bf16* __restrict__ buf, const f32x4 acc[2][4],
                                         const float* __restrict__ bias,
                                         int colbase, int lh, int lq) {
  #pragma unroll
  for (int g = 0; g < 4; ++g) {
    int col = g * 64 + colbase + lh;
    float bb = bias[col];
    #pragma unroll
    for (int mf = 0; mf < 2; ++mf) {
      int r = mf * 16 + lq * 4;
      #pragma unroll
      for (int c = 0; c < 4; ++c)
        buf[(r + c) * LDW + col] = (__bf16)(acc[mf][g][c] + bb);
    }
  }
}

// One projection k-loop: acc[mf][g] += A(LDS) @ W(packed global), dbuf prefetch.
__device__ __forceinline__ void proj(const __bf16* __restrict__ a0p,
                                     const __bf16* __restrict__ a1p,
                                     const __bf16* __restrict__ wB,  // lane offset folded in
                                     f32x4 acc[2][4]) {
  bf16x8 WB[2][4];
  #pragma unroll
  for (int g = 0; g < 4; ++g)
    WB[0][g] = *(const bf16x8*)(wB + (g * 8 + 0) * 512);
  #pragma unroll
  for (int kk = 0; kk < 8; ++kk) {
    const int cur = kk & 1, nxt = cur ^ 1;
    if (kk < 7) {
      #pragma unroll
      for (int g = 0; g < 4; ++g)
        WB[nxt][g] = *(const bf16x8*)(wB + (g * 8 + kk + 1) * 512);
    }
    bf16x8 a0 = *(const bf16x8*)(a0p + kk * 32);
    bf16x8 a1 = *(const bf16x8*)(a1p + kk * 32);
    #pragma unroll
    for (int g = 0; g < 4; ++g) {
      acc[0][g] = MFMA(a0, WB[cur][g], acc[0][g]);
      acc[1][g] = MFMA(a1, WB[cur][g], acc[1][g]);
    }
  }
}

__launch_bounds__(256, 4)
__global__ void fused_attn(const float* __restrict__ x, const __bf16* __restrict__ Wpk,
                           const float* __restrict__ bq, const float* __restrict__ bk,
                           const float* __restrict__ bv, const float* __restrict__ bo,
                           float* __restrict__ out) {
  __shared__ __bf16 sA[32 * LDW];   // x tile -> Q
  __shared__ __bf16 sB[32 * LDW];   // K -> Y
  __shared__ float PL[32 * 16];     // softmax probs [m][h][g]

  const int tid  = threadIdx.x;
  const int lane = tid & 63;
  const int nw   = tid >> 6;        // wave id = within-head col group j
  const int lh   = lane & 15;
  const int lq   = lane >> 4;
  const int cb   = nw * 16;         // colbase
  const int tok0 = blockIdx.x * 32;

  // ---- phase 1: stage x (lane-contiguous float4 -> bf16 padded LDS) ----
  const float4* xg = (const float4*)(x + (size_t)tok0 * 256);
  #pragma unroll
  for (int i = 0; i < 8; ++i) {
    int idx = i * 256 + tid;
    int row = idx >> 6;
    int c4  = idx & 63;
    float4 v = xg[idx];
    bf16x4 pk;
    pk[0] = (__bf16)v.x; pk[1] = (__bf16)v.y; pk[2] = (__bf16)v.z; pk[3] = (__bf16)v.w;
    *(bf16x4*)&sA[row * LDW + c4 * 4] = pk;
  }
  __syncthreads();

  const __bf16* a0p = sA + lh * LDW + lq * 8;
  const __bf16* a1p = a0p + 16 * LDW;
  const __bf16* wqB = Wpk + (size_t)((0 * 4 + nw) * 4 * 8) * 512 + lane * 8;
  const __bf16* wkB = Wpk + (size_t)((1 * 4 + nw) * 4 * 8) * 512 + lane * 8;
  const __bf16* wvB = Wpk + (size_t)((2 * 4 + nw) * 4 * 8) * 512 + lane * 8;
  const __bf16* woB = Wpk + (size_t)((3 * 4 + nw) * 4 * 8) * 512 + lane * 8;

  // ---- phase 2a: K k-loop, ka transient -> sB immediately ----
  {
    f32x4 ka[2][4];
    #pragma unroll
    for (int mf = 0; mf < 2; ++mf)
      #pragma unroll
      for (int g = 0; g < 4; ++g) ka[mf][g] = (f32x4){0.f, 0.f, 0.f, 0.f};
    proj(a0p, a1p, wkB, ka);
    store_cd(sB, ka, bk, cb, lh, lq);   // sB unread until softmax; own cols only
  }

  // ---- phase 2b: V k-loop, +bias, pack to bf16 (16 regs, long-lived) ----
  bf16x4 vb[2][4];
  {
    f32x4 va[2][4];
    #pragma unroll
    for (int mf = 0; mf < 2; ++mf)
      #pragma unroll
      for (int g = 0; g < 4; ++g) va[mf][g] = (f32x4){0.f, 0.f, 0.f, 0.f};
    proj(a0p, a1p, wvB, va);
    #pragma unroll
    for (int g = 0; g < 4; ++g) {
      float bb = bv[g * 64 + cb + lh];
      #pragma unroll
      for (int mf = 0; mf < 2; ++mf)
        #pragma unroll
        for (int c = 0; c < 4; ++c)
          vb[mf][g][c] = (__bf16)(va[mf][g][c] + bb);
    }
  }

  // ---- phase 2c: Q k-loop (qa short-lived: store right after barrier) ----
  f32x4 qa[2][4];
  #pragma unroll
  for (int mf = 0; mf < 2; ++mf)
    #pragma unroll
    for (int g = 0; g < 4; ++g) qa[mf][g] = (f32x4){0.f, 0.f, 0.f, 0.f};
  proj(a0p, a1p, wqB, qa);
  __syncthreads();   // all waves done reading x from sA

  // ---- phase 3: Q -> sA (x dead) ----
  store_cd(sA, qa, bq, cb, lh, lq);
  __syncthreads();   // Q, K visible

  // ---- phase 4: scores + softmax (4 active threads of 8 per token) ----
  {
    const int m   = tid >> 3;
    const int sub = tid & 7;
    if (sub < 4) {
      const int h = sub;
      float d0 = 0.f, d1 = 0.f, d2 = 0.f, d3 = 0.f;
      #pragma unroll
      for (int i = 0; i < 8; ++i) {
        bf16x8 qv = *(const bf16x8*)&sA[m * LDW + h * 64 + i * 8];
        bf16x8 k0 = *(const bf16x8*)&sB[m * LDW +   0 + i * 8];
        bf16x8 k1 = *(const bf16x8*)&sB[m * LDW +  64 + i * 8];
        bf16x8 k2 = *(const bf16x8*)&sB[m * LDW + 128 + i * 8];
        bf16x8 k3 = *(const bf16x8*)&sB[m * LDW + 192 + i * 8];
        #pragma unroll
        for (int c = 0; c < 8; ++c) {
          float qf = (float)qv[c];
          d0 += qf * (float)k0[c];
          d1 += qf * (float)k1[c];
          d2 += qf * (float)k2[c];
          d3 += qf * (float)k3[c];
        }
      }
      d0 *= 0.125f; d1 *= 0.125f; d2 *= 0.125f; d3 *= 0.125f;  // 1/sqrt(64)
      float mx = fmaxf(fmaxf(d0, d1), fmaxf(d2, d3));
      float e0 = expf(d0 - mx), e1 = expf(d1 - mx), e2 = expf(d2 - mx), e3 = expf(d3 - mx);
      float inv = 1.0f / (e0 + e1 + e2 + e3);
      float* pl = &PL[m * 16 + h * 4];
      pl[0] = e0 * inv; pl[1] = e1 * inv; pl[2] = e2 * inv; pl[3] = e3 * inv;
    }
  }
  __syncthreads();   // PL visible; K reads complete (sB reusable)

  // ---- prefetch first two O k-slices (overlaps mix + barrier) ----
  bf16x8 WB[2][4];
  #pragma unroll
  for (int g = 0; g < 4; ++g) {
    WB[0][g] = *(const bf16x8*)(woB + (g * 8 + 0) * 512);
    WB[1][g] = *(const bf16x8*)(woB + (g * 8 + 1) * 512);
  }

  // ---- phase 5: in-register head-mix (vb holds all 4 heads), Y -> sB ----
  {
    #pragma unroll
    for (int mf = 0; mf < 2; ++mf) {
      #pragma unroll
      for (int c = 0; c < 4; ++c) {
        int m = mf * 16 + lq * 4 + c;
        const float v0 = (float)vb[mf][0][c];
        const float v1 = (float)vb[mf][1][c];
        const float v2 = (float)vb[mf][2][c];
        const float v3 = (float)vb[mf][3][c];
        const float* pl = &PL[m * 16];
        #pragma unroll
        for (int h = 0; h < 4; ++h) {
          float y = pl[h*4+0] * v0 + pl[h*4+1] * v1 + pl[h*4+2] * v2 + pl[h*4+3] * v3;
          sB[(m) * LDW + h * 64 + cb + lh] = (__bf16)y;
        }
      }
    }
  }
  __syncthreads();   // Y visible

  // ---- phase 6: O-GEMM (A from sB), distance-2 prefetch into WB[cur] ----
  {
    const __bf16* yp0 = sB + lh * LDW + lq * 8;
    const __bf16* yp1 = yp0 + 16 * LDW;
    f32x4 acc[2][4];
    #pragma unroll
    for (int mf = 0; mf < 2; ++mf)
      #pragma unroll
      for (int g = 0; g < 4; ++g) acc[mf][g] = (f32x4){0.f, 0.f, 0.f, 0.f};

    #pragma unroll
    for (int kk = 0; kk < 8; ++kk) {
      const int cur = kk & 1;
      bf16x8 a0 = *(const bf16x8*)(yp0 + kk * 32);
      bf16x8 a1 = *(const bf16x8*)(yp1 + kk * 32);
      #pragma unroll
      for (int g = 0; g < 4; ++g) {
        acc[0][g] = MFMA(a0, WB[cur][g], acc[0][g]);
        acc[1][g] = MFMA(a1, WB[cur][g], acc[1][g]);
      }
      if (kk < 6) {
        #pragma unroll
        for (int g = 0; g < 4; ++g)
          WB[cur][g] = *(const bf16x8*)(woB + (g * 8 + kk + 2) * 512);
      }
    }

    #pragma unroll
    for (int g = 0; g < 4; ++g) {
      int col = g * 64 + cb + lh;
      float bb = bo[col];
      #pragma unroll
      for (int mf = 0; mf < 2; ++mf) {
        int rbase = tok0 + mf * 16 + lq * 4;
        #pragma unroll
        for (int c = 0; c < 4; ++c)
          out[(size_t)(rbase + c) * 256 + col] = acc[mf][g][c] + bb;
      }
    }
  }
}

extern "C" void kernel_launch(void* const* d_in, const int* in_sizes, int n_in,
                              void* d_out, int out_size, void* d_ws, size_t ws_size,
                              hipStream_t stream) {
  const float* x  = (const float*)d_in[0];
  const float* Wq = (const float*)d_in[1];
  const float* bq = (const float*)d_in[2];
  const float* Wk = (const float*)d_in[3];
  const float* bk = (const float*)d_in[4];
  const float* Wv = (const float*)d_in[5];
  const float* bv = (const float*)d_in[6];
  const float* Wo = (const float*)d_in[7];
  const float* bo = (const float*)d_in[8];
  float* out = (float*)d_out;
  __bf16* Wpk = (__bf16*)d_ws;   // 512 frags x 1 KB

  pack_wfrag<<<dim3(512), dim3(64), 0, stream>>>(Wq, Wk, Wv, Wo, Wpk);
  fused_attn<<<dim3(1024), dim3(256), 0, stream>>>(x, Wpk, bq, bk, bv, bo, out);
}

// Round 8
// 134.123 us; speedup vs baseline: 1.2395x; 1.2395x over previous
//
#include <hip/hip_runtime.h>

// B=8, S=4096, E=256, H=4, DK=64. Tokens = 32768.
// Head-mix "attention": 4 GEMMs (32768x256 @ 256x256) + per-token 4x4 softmax.
// Round-8: two-tile blocks (M=64) -> weight traffic halved, 16 MFMA/kk/wave.
//   512 blocks x 256 thr; LDS exactly 64 KB -> 2 blocks/CU (8 waves, 2/SIMD)
//   -> VGPR cap 256 (launch_bounds(256,2)) -> no spills (round-6/7 lesson).
//   Distance-3 ring prefetch of weight frags (cap-256 headroom pays for it).
//   All LDS tiles in fragment-contiguous layout (unpadded, lane-linear b128):
//     xA[t]: x frags -> Q frags -> (PL overlays tile-0 region post-softmax)
//     sK[t]: K frags -> Y frags.   V lives in regs as bf16 (32 VGPRs).

typedef __bf16 bf16x8 __attribute__((ext_vector_type(8)));
typedef __bf16 bf16x4 __attribute__((ext_vector_type(4)));
typedef float f32x4 __attribute__((ext_vector_type(4)));

#define MFMA(a, b, c) __builtin_amdgcn_mfma_f32_16x16x32_bf16((a), (b), (c), 0, 0, 0)

// ---------- prep: pack W into fragment-contiguous bf16, interleaved-n ----------
// frag (p, j, g, kk): lane (lh=lane&15, lq=lane>>4) holds
//   W_p[g*64 + j*16 + lh][kk*32 + lq*8 .. +8)   (16 B)
// at Wpk[frag_id*512 + lane*8], frag_id = ((p*4+j)*4+g)*8+kk.   (unchanged r6/r7)
__global__ void pack_wfrag(const float* __restrict__ Wq, const float* __restrict__ Wk,
                           const float* __restrict__ Wv, const float* __restrict__ Wo,
                           __bf16* __restrict__ Wpk) {
  const int f    = blockIdx.x;          // 0..511
  const int lane = threadIdx.x;         // 0..63
  const int kk = f & 7;
  const int g  = (f >> 3) & 3;
  const int j  = (f >> 5) & 3;
  const int p  = f >> 7;
  const float* W = (p == 0) ? Wq : (p == 1) ? Wk : (p == 2) ? Wv : Wo;
  const int lh = lane & 15, lq = lane >> 4;
  const int n  = g * 64 + j * 16 + lh;
  const int k0 = kk * 32 + lq * 8;
  const float4 s0 = *(const float4*)&W[n * 256 + k0];
  const float4 s1 = *(const float4*)&W[n * 256 + k0 + 4];
  bf16x8 r;
  r[0] = (__bf16)s0.x; r[1] = (__bf16)s0.y; r[2] = (__bf16)s0.z; r[3] = (__bf16)s0.w;
  r[4] = (__bf16)s1.x; r[5] = (__bf16)s1.y; r[6] = (__bf16)s1.z; r[7] = (__bf16)s1.w;
  *(bf16x8*)&Wpk[(size_t)f * 512 + lane * 8] = r;
}

// Two-tile projection K-loop: acc_t[mf][g] += A_t @ W, distance-3 ring prefetch.
// A0/A1 point at xAs[t*8192 + lane*8]; frag (mf,kk) at offset (mf*8+kk)*512.
__device__ __forceinline__ void proj2(const __bf16* __restrict__ A0,
                                      const __bf16* __restrict__ A1,
                                      const __bf16* __restrict__ wB,   // lane*8 folded in
                                      f32x4 a0[2][4], f32x4 a1[2][4]) {
  bf16x8 WB[4][4];
  #pragma unroll
  for (int kk = 0; kk < 3; ++kk)
    #pragma unroll
    for (int g = 0; g < 4; ++g)
      WB[kk][g] = *(const bf16x8*)(wB + (g * 8 + kk) * 512);
  #pragma unroll
  for (int kk = 0; kk < 8; ++kk) {
    if (kk < 5) {   // prefetch kk+3 into slot (kk+3)&3 == (kk-1)&3 (dead) — safe pre-MFMA
      #pragma unroll
      for (int g = 0; g < 4; ++g)
        WB[(kk + 3) & 3][g] = *(const bf16x8*)(wB + (g * 8 + kk + 3) * 512);
    }
    bf16x8 x00 = *(const bf16x8*)(A0 + kk * 512);
    bf16x8 x01 = *(const bf16x8*)(A0 + (8 + kk) * 512);
    bf16x8 x10 = *(const bf16x8*)(A1 + kk * 512);
    bf16x8 x11 = *(const bf16x8*)(A1 + (8 + kk) * 512);
    #pragma unroll
    for (int g = 0; g < 4; ++g) {
      a0[0][g] = MFMA(x00, WB[kk & 3][g], a0[0][g]);
      a0[1][g] = MFMA(x01, WB[kk & 3][g], a0[1][g]);
      a1[0][g] = MFMA(x10, WB[kk & 3][g], a1[0][g]);
      a1[1][g] = MFMA(x11, WB[kk & 3][g], a1[1][g]);
    }
  }
}

// C/D (+bias) -> fragment-layout LDS tile. Element (row=mf*16+lq*4+c,
// col=g*64+cb+lh) lands at frag (mf*8 + col>>5), lane' = ((col>>3)&3)*16 + row&15, byte col&7.
__device__ __forceinline__ void store_frag(__bf16* __restrict__ dst, const f32x4 acc[2][4],
                                           const float* __restrict__ bias,
                                           int cb, int lh, int lq) {
  #pragma unroll
  for (int g = 0; g < 4; ++g) {
    int col = g * 64 + cb + lh;
    float bb = bias[col];
    int kk = col >> 5, lqt = (col >> 3) & 3, j = col & 7;
    #pragma unroll
    for (int mf = 0; mf < 2; ++mf)
      #pragma unroll
      for (int c = 0; c < 4; ++c) {
        int rr = lq * 4 + c;
        dst[(mf * 8 + kk) * 512 + (lqt * 16 + rr) * 8 + j] = (__bf16)(acc[mf][g][c] + bb);
      }
  }
}

__launch_bounds__(256, 2)
__global__ void fused_attn(const float* __restrict__ x, const __bf16* __restrict__ Wpk,
                           const float* __restrict__ bq, const float* __restrict__ bk,
                           const float* __restrict__ bv, const float* __restrict__ bo,
                           float* __restrict__ out) {
  __shared__ __bf16 xAs[2 * 8192];   // x frags -> Q frags; PL overlays [0..2047] post-softmax
  __shared__ __bf16 sKs[2 * 8192];   // K frags -> Y frags

  const int tid  = threadIdx.x;
  const int lane = tid & 63;
  const int nw   = tid >> 6;
  const int lh   = lane & 15;
  const int lq   = lane >> 4;
  const int cb   = nw * 16;
  const long tok0 = (long)blockIdx.x * 64;

  // ---- stage x (2 tiles) into A-fragment layout ----
  #pragma unroll
  for (int t = 0; t < 2; ++t) {
    const float4* xt = (const float4*)(x + (tok0 + t * 32) * 256);
    #pragma unroll
    for (int i = 0; i < 8; ++i) {
      int row = tid >> 3;                // 0..31
      int k4  = (tid & 7) + 8 * i;       // 0..63
      float4 v = xt[row * 64 + k4];
      int kk = k4 >> 3, lqt = (k4 >> 1) & 3, j0 = (k4 & 1) * 4, mf = row >> 4;
      bf16x4 pk;
      pk[0] = (__bf16)v.x; pk[1] = (__bf16)v.y; pk[2] = (__bf16)v.z; pk[3] = (__bf16)v.w;
      *(bf16x4*)&xAs[t * 8192 + (mf * 8 + kk) * 512 + (lqt * 16 + (row & 15)) * 8 + j0] = pk;
    }
  }
  __syncthreads();   // B1

  const __bf16* A0 = xAs + lane * 8;
  const __bf16* A1 = xAs + 8192 + lane * 8;
  const __bf16* wq = Wpk + (size_t)(0 * 4 + nw) * 32 * 512 + lane * 8;
  const __bf16* wk = Wpk + (size_t)(1 * 4 + nw) * 32 * 512 + lane * 8;
  const __bf16* wv = Wpk + (size_t)(2 * 4 + nw) * 32 * 512 + lane * 8;
  const __bf16* wo = Wpk + (size_t)(3 * 4 + nw) * 32 * 512 + lane * 8;

  // ---- K (transient -> sK frags) ----
  {
    f32x4 k0a[2][4], k1a[2][4];
    #pragma unroll
    for (int mf = 0; mf < 2; ++mf)
      #pragma unroll
      for (int g = 0; g < 4; ++g) { k0a[mf][g] = (f32x4){0,0,0,0}; k1a[mf][g] = (f32x4){0,0,0,0}; }
    proj2(A0, A1, wk, k0a, k1a);
    store_frag(sKs, k0a, bk, cb, lh, lq);
    store_frag(sKs + 8192, k1a, bk, cb, lh, lq);
  }

  // ---- V (-> bf16 regs, all 4 heads per lane) ----
  bf16x4 vb[2][2][4];
  {
    f32x4 v0a[2][4], v1a[2][4];
    #pragma unroll
    for (int mf = 0; mf < 2; ++mf)
      #pragma unroll
      for (int g = 0; g < 4; ++g) { v0a[mf][g] = (f32x4){0,0,0,0}; v1a[mf][g] = (f32x4){0,0,0,0}; }
    proj2(A0, A1, wv, v0a, v1a);
    #pragma unroll
    for (int g = 0; g < 4; ++g) {
      float bb = bv[g * 64 + cb + lh];
      #pragma unroll
      for (int mf = 0; mf < 2; ++mf)
        #pragma unroll
        for (int c = 0; c < 4; ++c) {
          vb[0][mf][g][c] = (__bf16)(v0a[mf][g][c] + bb);
          vb[1][mf][g][c] = (__bf16)(v1a[mf][g][c] + bb);
        }
    }
  }

  // ---- Q (held in regs until x dead) ----
  f32x4 q0a[2][4], q1a[2][4];
  #pragma unroll
  for (int mf = 0; mf < 2; ++mf)
    #pragma unroll
    for (int g = 0; g < 4; ++g) { q0a[mf][g] = (f32x4){0,0,0,0}; q1a[mf][g] = (f32x4){0,0,0,0}; }
  proj2(A0, A1, wq, q0a, q1a);
  __syncthreads();   // B2: all xA reads complete

  store_frag(xAs, q0a, bq, cb, lh, lq);          // Q -> tile-0 region
  store_frag(xAs + 8192, q1a, bq, cb, lh, lq);   // Q -> tile-1 region
  __syncthreads();   // B3: Q,K visible

  // ---- softmax: 256 threads = 64 tokens x 4 heads ----
  float* PLp = (float*)xAs;   // PL[m][h][g], 4 KB, overlays tile-0 Q AFTER B4
  {
    const int m = tid >> 2, h = tid & 3;
    const int t = m >> 5, mf = (m >> 4) & 1, mm = m & 15;
    const __bf16* Qb = xAs + t * 8192 + mf * 8 * 512;
    const __bf16* Kb = sKs + t * 8192 + mf * 8 * 512;
    float d0 = 0.f, d1 = 0.f, d2 = 0.f, d3 = 0.f;
    #pragma unroll
    for (int i = 0; i < 8; ++i) {
      int lp = ((i & 3) * 16 + mm) * 8;
      int iq = (i >> 2) * 512;
      bf16x8 qv = *(const bf16x8*)(Qb + (h * 2) * 512 + iq + lp);
      bf16x8 k0 = *(const bf16x8*)(Kb + 0 * 1024 + iq + lp);
      bf16x8 k1 = *(const bf16x8*)(Kb + 1 * 1024 + iq + lp);
      bf16x8 k2 = *(const bf16x8*)(Kb + 2 * 1024 + iq + lp);
      bf16x8 k3 = *(const bf16x8*)(Kb + 3 * 1024 + iq + lp);
      #pragma unroll
      for (int c = 0; c < 8; ++c) {
        float qf = (float)qv[c];
        d0 += qf * (float)k0[c];
        d1 += qf * (float)k1[c];
        d2 += qf * (float)k2[c];
        d3 += qf * (float)k3[c];
      }
    }
    d0 *= 0.125f; d1 *= 0.125f; d2 *= 0.125f; d3 *= 0.125f;   // 1/sqrt(64)
    float mx = fmaxf(fmaxf(d0, d1), fmaxf(d2, d3));
    float e0 = expf(d0 - mx), e1 = expf(d1 - mx), e2 = expf(d2 - mx), e3 = expf(d3 - mx);
    float inv = 1.0f / (e0 + e1 + e2 + e3);
    __syncthreads();   // B4: all Q/K reads done; tile-0 Q region now dead
    f32x4 pv; pv[0] = e0 * inv; pv[1] = e1 * inv; pv[2] = e2 * inv; pv[3] = e3 * inv;
    *(f32x4*)&PLp[m * 16 + h * 4] = pv;
  }
  __syncthreads();   // B5: PL visible; K dead (sK reusable)

  // ---- head-mix in registers -> Y frags into sK ----
  #pragma unroll
  for (int t = 0; t < 2; ++t)
    #pragma unroll
    for (int mf = 0; mf < 2; ++mf)
      #pragma unroll
      for (int c = 0; c < 4; ++c) {
        int rr = lq * 4 + c;
        int m = t * 32 + mf * 16 + rr;
        f32x4 P0 = *(const f32x4*)&PLp[m * 16 + 0];
        f32x4 P1 = *(const f32x4*)&PLp[m * 16 + 4];
        f32x4 P2 = *(const f32x4*)&PLp[m * 16 + 8];
        f32x4 P3 = *(const f32x4*)&PLp[m * 16 + 12];
        float v0 = (float)vb[t][mf][0][c], v1 = (float)vb[t][mf][1][c];
        float v2 = (float)vb[t][mf][2][c], v3 = (float)vb[t][mf][3][c];
        #pragma unroll
        for (int h = 0; h < 4; ++h) {
          f32x4 P = (h == 0) ? P0 : (h == 1) ? P1 : (h == 2) ? P2 : P3;
          float y = P[0] * v0 + P[1] * v1 + P[2] * v2 + P[3] * v3;
          int col = h * 64 + cb + lh;
          int kk = col >> 5, lqt = (col >> 3) & 3, j = col & 7;
          sKs[t * 8192 + (mf * 8 + kk) * 512 + (lqt * 16 + rr) * 8 + j] = (__bf16)y;
        }
      }
  __syncthreads();   // B6: Y visible

  // ---- O-GEMM: A = Y frags from sK ----
  {
    f32x4 o0a[2][4], o1a[2][4];
    #pragma unroll
    for (int mf = 0; mf < 2; ++mf)
      #pragma unroll
      for (int g = 0; g < 4; ++g) { o0a[mf][g] = (f32x4){0,0,0,0}; o1a[mf][g] = (f32x4){0,0,0,0}; }
    proj2(sKs + lane * 8, sKs + 8192 + lane * 8, wo, o0a, o1a);

    #pragma unroll
    for (int g = 0; g < 4; ++g) {
      int col = g * 64 + cb + lh;
      float bb = bo[col];
      #pragma unroll
      for (int mf = 0; mf < 2; ++mf)
        #pragma unroll
        for (int c = 0; c < 4; ++c) {
          long r0 = tok0 + mf * 16 + lq * 4 + c;
          out[r0 * 256 + col]        = o0a[mf][g][c] + bb;
          out[(r0 + 32) * 256 + col] = o1a[mf][g][c] + bb;
        }
    }
  }
}

extern "C" void kernel_launch(void* const* d_in, const int* in_sizes, int n_in,
                              void* d_out, int out_size, void* d_ws, size_t ws_size,
                              hipStream_t stream) {
  const float* x  = (const float*)d_in[0];
  const float* Wq = (const float*)d_in[1];
  const float* bq = (const float*)d_in[2];
  const float* Wk = (const float*)d_in[3];
  const float* bk = (const float*)d_in[4];
  const float* Wv = (const float*)d_in[5];
  const float* bv = (const float*)d_in[6];
  const float* Wo = (const float*)d_in[7];
  const float* bo = (const float*)d_in[8];
  float* out = (float*)d_out;
  __bf16* Wpk = (__bf16*)d_ws;   // 512 frags x 1 KB

  pack_wfrag<<<dim3(512), dim3(64), 0, stream>>>(Wq, Wk, Wv, Wo, Wpk);
  fused_attn<<<dim3(512), dim3(256), 0, stream>>>(x, Wpk, bq, bk, bv, bo, out);
}